// Round 6
// baseline (172.747 us; speedup 1.0000x reference)
//
#include <hip/hip_runtime.h>

// x: (128, 55, 55, 96) NHWC fp32; kernel: (96, 5, 5) fp32 depthwise; out = x + dwconv(x,k)
#define NB 128
#define HW 55
#define IMG (HW * HW)           // 3025
#define CH 96
#define GROUPS (CH / 4)         // 24 float4 channel-groups
#define TAPS 25
#define WSTRIDE CH              // 96 floats
#define HSTRIDE (HW * CH)       // 5280 floats
#define NPIX (NB * IMG)         // 387,200 pixels
#define TOTALF4 (NPIX * GROUPS) // 9,292,800 float4 items
#define NWG (TOTALF4 / 256)     // 36,300 blocks (exact)
#define NXCD 8
#define NSLOTCAP 32             // tap-slot capacity (>= TAPS rounded to 8)

// ---- workspace layout ----
// float4 wslot[NSLOTCAP][GROUPS] : compacted nonzero-tap weights (pad = 0)
// int2   oslot[NSLOTCAP][GROUPS] : {float-offset, (dh+2)<<8 | (dw+2)} (pad = {0, center})
// int    ntap[GROUPS]            : nonzero-tap count per group
// int    tapmask[GROUPS]         : 1 if group has any nonzero tap
// int    nslotmax                : max ntap, rounded up to multiple of 8
// int    acount[3]               : active items per 256-item window, per phase
// int    atab[3*256]             : active item slots (i in [0,256)) per phase
//
// Phase math: item base of block B is B*256; (B*256)%24 has period 3 in B
// (256%24==16): offsets {0,16,8}. So only 3 distinct active-slot patterns exist.

__global__ void repack_kernel(const float* __restrict__ k,
                              float4* __restrict__ wslot,
                              int2* __restrict__ oslot,
                              int* __restrict__ ntap,
                              int* __restrict__ tapmask,
                              int* __restrict__ nslotmax,
                              int* __restrict__ acount,
                              int* __restrict__ atab) {
    int g = threadIdx.x;
    if (g < GROUPS) {
        int ns = 0;
        for (int tap = 0; tap < TAPS; ++tap) {
            float w0 = k[(4 * g + 0) * TAPS + tap];
            float w1 = k[(4 * g + 1) * TAPS + tap];
            float w2 = k[(4 * g + 2) * TAPS + tap];
            float w3 = k[(4 * g + 3) * TAPS + tap];
            if (w0 != 0.f || w1 != 0.f || w2 != 0.f || w3 != 0.f) {
                int dh = tap / 5 - 2, dw = tap % 5 - 2;
                wslot[ns * GROUPS + g] = make_float4(w0, w1, w2, w3);
                oslot[ns * GROUPS + g] =
                    make_int2(dh * HSTRIDE + dw * WSTRIDE, ((dh + 2) << 8) | (dw + 2));
                ++ns;
            }
        }
        ntap[g] = ns;
        tapmask[g] = (ns > 0) ? 1 : 0;
        for (int s = ns; s < NSLOTCAP; ++s) {            // pads contribute exactly 0
            wslot[s * GROUPS + g] = make_float4(0.f, 0.f, 0.f, 0.f);
            oslot[s * GROUPS + g] = make_int2(0, (2 << 8) | 2);
        }
    }
    __syncthreads();
    if (threadIdx.x == 0) {
        int m = 0;
        for (int gg = 0; gg < GROUPS; ++gg) m = m > ntap[gg] ? m : ntap[gg];
        *nslotmax = (m + 7) & ~7;                        // 0 if kernel all-zero
        for (int P = 0; P < 3; ++P) {
            int off = (P * 16) % GROUPS;                 // {0,16,8}
            int na = 0;
            for (int i = 0; i < 256; ++i) {
                int gg = (off + i) % GROUPS;
                if (tapmask[gg]) atab[P * 256 + na++] = i;
            }
            acount[P] = na;
        }
    }
}

// ---- fused kernel: wave-specialized ----
// All lanes: coalesced residual load; inactive-group lanes store immediately
// (pure stream). Wave 0 alone processes the block's active items (conv + store).
// Each item stored exactly once; no barriers needed.
__global__ __launch_bounds__(256, 4) void fused_kernel(const float* __restrict__ x,
                                                       const float4* __restrict__ wslot,
                                                       const int2* __restrict__ oslot,
                                                       const int* __restrict__ tapmask,
                                                       const int* __restrict__ nslotmax,
                                                       const int* __restrict__ acount,
                                                       const int* __restrict__ atab,
                                                       float* __restrict__ out) {
    // Bijective chunked XCD swizzle (m204): contiguous grid ranges per XCD.
    const int q = NWG / NXCD, r = NWG % NXCD;
    int xcd = blockIdx.x & (NXCD - 1);
    int idx = blockIdx.x >> 3;
    int swz = (xcd < r ? xcd * (q + 1) : r * (q + 1) + (xcd - r) * q) + idx;

    const int itembase = swz * 256;
    const int tid = threadIdx.x;
    int item = itembase + tid;
    int g = item % GROUPS;
    int pixel = item / GROUPS;
    int base = pixel * CH + g * 4;
    float4 xc = *reinterpret_cast<const float4*>(x + base);

    if (tapmask[g] == 0) {                   // pure-copy lanes: stream out now
        __builtin_nontemporal_store(xc.x, out + base + 0);
        __builtin_nontemporal_store(xc.y, out + base + 1);
        __builtin_nontemporal_store(xc.z, out + base + 2);
        __builtin_nontemporal_store(xc.w, out + base + 3);
    }

    if (tid < 64) {                          // wave 0: handle active items
        const int phase = swz % 3;
        const int na = acount[phase];
        const int nmax = *nslotmax;
        for (int j = tid; j < na; j += 64) {
            int ai = atab[phase * 256 + j];
            int aitem = itembase + ai;
            int ag = aitem % GROUPS;
            int apix = aitem / GROUPS;
            int arem = apix % IMG;
            int ah = arem / HW;
            int aw = arem - ah * HW;
            int abase = apix * CH + ag * 4;
            float4 acc = *reinterpret_cast<const float4*>(x + abase);  // L1-hot

            const int2* orow = oslot + ag;
            const float4* wrow = wslot + ag;
            for (int s0 = 0; s0 < nmax; s0 += 8) {
                int2 om[8];
                float4 wv[8];
                float sc[8];
                float4 xv[8];
#pragma unroll
                for (int si = 0; si < 8; ++si) om[si] = orow[(s0 + si) * GROUPS];
#pragma unroll
                for (int si = 0; si < 8; ++si) wv[si] = wrow[(s0 + si) * GROUPS];
#pragma unroll
                for (int si = 0; si < 8; ++si) {
                    const int dh2 = (om[si].y >> 8) & 0xFF;
                    const int dw2 = om[si].y & 0xFF;
                    const bool valid = ((unsigned)(ah + dh2 - 2) < (unsigned)HW) &
                                       ((unsigned)(aw + dw2 - 2) < (unsigned)HW);
                    sc[si] = valid ? 1.0f : 0.0f;
                    const int off = valid ? om[si].x : 0;
                    xv[si] = *reinterpret_cast<const float4*>(x + abase + off);
                }
#pragma unroll
                for (int si = 0; si < 8; ++si) {
                    acc.x += (wv[si].x * sc[si]) * xv[si].x;
                    acc.y += (wv[si].y * sc[si]) * xv[si].y;
                    acc.z += (wv[si].z * sc[si]) * xv[si].z;
                    acc.w += (wv[si].w * sc[si]) * xv[si].w;
                }
            }
            __builtin_nontemporal_store(acc.x, out + abase + 0);
            __builtin_nontemporal_store(acc.y, out + abase + 1);
            __builtin_nontemporal_store(acc.z, out + abase + 2);
            __builtin_nontemporal_store(acc.w, out + abase + 3);
        }
    }
}

// ---- Fallback (ws too small): monolithic, reads raw k — correctness only ----
__global__ __launch_bounds__(256) void fallback_kernel(const float* __restrict__ x,
                                                       const float* __restrict__ kraw,
                                                       float* __restrict__ out) {
    int t = blockIdx.x * 256 + threadIdx.x;
    if (t >= TOTALF4) return;
    int g = t % GROUPS;
    int pixel = t / GROUPS;
    int rem = pixel % IMG;
    int h = rem / HW;
    int w = rem - h * HW;
    int base = pixel * CH + g * 4;
    const float4 xc = *reinterpret_cast<const float4*>(x + base);
    float4 acc = make_float4(xc.x, xc.y, xc.z, xc.w);
#pragma unroll
    for (int dh = -2; dh <= 2; ++dh)
#pragma unroll
        for (int dw = -2; dw <= 2; ++dw) {
            const int tap = (dh + 2) * 5 + (dw + 2);
            const bool valid = ((unsigned)(h + dh) < (unsigned)HW) &
                               ((unsigned)(w + dw) < (unsigned)HW);
            const float vs = valid ? 1.0f : 0.0f;
            const int off = valid ? (dh * HSTRIDE + dw * WSTRIDE) : 0;
            const float4 xv = *reinterpret_cast<const float4*>(x + base + off);
            acc.x += (kraw[(g * 4 + 0) * TAPS + tap] * vs) * xv.x;
            acc.y += (kraw[(g * 4 + 1) * TAPS + tap] * vs) * xv.y;
            acc.z += (kraw[(g * 4 + 2) * TAPS + tap] * vs) * xv.z;
            acc.w += (kraw[(g * 4 + 3) * TAPS + tap] * vs) * xv.w;
        }
    *reinterpret_cast<float4*>(out + base) = acc;
}

extern "C" void kernel_launch(void* const* d_in, const int* in_sizes, int n_in,
                              void* d_out, int out_size, void* d_ws, size_t ws_size,
                              hipStream_t stream) {
    const float* x = (const float*)d_in[0];
    const float* k = (const float*)d_in[1];
    float* out = (float*)d_out;

    const size_t sz_wslot = (size_t)NSLOTCAP * GROUPS * sizeof(float4);
    const size_t sz_oslot = (size_t)NSLOTCAP * GROUPS * sizeof(int2);
    const size_t sz_ntap = GROUPS * sizeof(int);
    const size_t sz_mask = GROUPS * sizeof(int);
    const size_t sz_nsm = sizeof(int);
    const size_t sz_acount = 3 * sizeof(int);
    const size_t sz_atab = 3 * 256 * sizeof(int);
    const size_t ws_need = sz_wslot + sz_oslot + sz_ntap + sz_mask + sz_nsm +
                           sz_acount + sz_atab;

    if (ws_size >= ws_need) {
        char* p = (char*)d_ws;
        float4* wslot = (float4*)p;   p += sz_wslot;
        int2* oslot = (int2*)p;       p += sz_oslot;
        int* ntap = (int*)p;          p += sz_ntap;
        int* tapmask = (int*)p;       p += sz_mask;
        int* nslotmax = (int*)p;      p += sz_nsm;
        int* acount = (int*)p;        p += sz_acount;
        int* atab = (int*)p;

        repack_kernel<<<1, 64, 0, stream>>>(k, wslot, oslot, ntap, tapmask,
                                            nslotmax, acount, atab);
        fused_kernel<<<NWG, 256, 0, stream>>>(x, wslot, oslot, tapmask,
                                              nslotmax, acount, atab, out);
    } else {
        fallback_kernel<<<NWG, 256, 0, stream>>>(x, k, out);
    }
}

// Round 7
// 119.662 us; speedup vs baseline: 1.4436x; 1.4436x over previous
//
#include <hip/hip_runtime.h>

// x: (128, 55, 55, 96) NHWC fp32; kernel: (96, 5, 5) fp32 depthwise; out = x + dwconv(x,k)
#define NB 128
#define HW 55
#define IMG (HW * HW)           // 3025
#define CH 96
#define GROUPS (CH / 4)         // 24 float4 channel-groups
#define TAPS 25
#define WSTRIDE CH              // 96 floats
#define HSTRIDE (HW * CH)       // 5280 floats
#define NPIX (NB * IMG)         // 387,200 pixels
#define TOTALF4 (NPIX * GROUPS) // 9,292,800 float4 items
#define NWG (TOTALF4 / 256)     // 36,300 blocks (exact)
#define NXCD 8
#define NSLOTCAP 32             // capacity: up to 32 nonzero taps (generality)
#define NBATCH (NSLOTCAP / 8)   // 4 batches of 8 slots

// ---- workspace layout ----
// float4 wvtab[NBATCH*8][GROUPS] : compacted nonzero-tap weights (pad = 0)
// int4   offtab[NBATCH][GROUPS]  : 8 x s16 packed float-offsets per batch
// int2   dhwtab[NBATCH][GROUPS]  : 8 x byte ((dh+2)<<4 | (dw+2)) per batch
// int    ntap[GROUPS]            : nonzero-tap count per group
// int    nbmax                   : ceil(max ntap / 8) (0 if all-zero kernel)

__global__ void repack_kernel(const float* __restrict__ k,
                              float4* __restrict__ wvtab,
                              int4* __restrict__ offtab,
                              int2* __restrict__ dhwtab,
                              int* __restrict__ ntap,
                              int* __restrict__ nbmax) {
    int g = threadIdx.x;
    if (g < GROUPS) {
        int off16[NSLOTCAP];
        int dby[NSLOTCAP];
        float4 wv[NSLOTCAP];
        int ns = 0;
        for (int tap = 0; tap < TAPS; ++tap) {
            float w0 = k[(4 * g + 0) * TAPS + tap];
            float w1 = k[(4 * g + 1) * TAPS + tap];
            float w2 = k[(4 * g + 2) * TAPS + tap];
            float w3 = k[(4 * g + 3) * TAPS + tap];
            if (w0 != 0.f || w1 != 0.f || w2 != 0.f || w3 != 0.f) {
                int dh = tap / 5 - 2, dw = tap % 5 - 2;
                off16[ns] = dh * HSTRIDE + dw * WSTRIDE;   // fits s16 (|.|<=10752)
                dby[ns] = ((dh + 2) << 4) | (dw + 2);
                wv[ns] = make_float4(w0, w1, w2, w3);
                ++ns;
            }
        }
        ntap[g] = ns;
        for (int s = ns; s < NSLOTCAP; ++s) {              // pads contribute 0
            off16[s] = 0;
            dby[s] = (2 << 4) | 2;
            wv[s] = make_float4(0.f, 0.f, 0.f, 0.f);
        }
        for (int b = 0; b < NBATCH; ++b) {
            int4 of;
            of.x = (off16[8 * b + 0] & 0xFFFF) | (off16[8 * b + 1] << 16);
            of.y = (off16[8 * b + 2] & 0xFFFF) | (off16[8 * b + 3] << 16);
            of.z = (off16[8 * b + 4] & 0xFFFF) | (off16[8 * b + 5] << 16);
            of.w = (off16[8 * b + 6] & 0xFFFF) | (off16[8 * b + 7] << 16);
            offtab[b * GROUPS + g] = of;
            int2 dd;
            dd.x = dby[8 * b + 0] | (dby[8 * b + 1] << 8) |
                   (dby[8 * b + 2] << 16) | (dby[8 * b + 3] << 24);
            dd.y = dby[8 * b + 4] | (dby[8 * b + 5] << 8) |
                   (dby[8 * b + 6] << 16) | (dby[8 * b + 7] << 24);
            dhwtab[b * GROUPS + g] = dd;
            for (int si = 0; si < 8; ++si)
                wvtab[(b * 8 + si) * GROUPS + g] = wv[8 * b + si];
        }
    }
    __syncthreads();
    if (threadIdx.x == 0) {
        int m = 0;
        for (int gg = 0; gg < GROUPS; ++gg) m = m > ntap[gg] ? m : ntap[gg];
        *nbmax = (m + 7) / 8;
    }
}

// slot helper: from packed s16 offset + dhw byte -> clamped address + scale
__device__ __forceinline__ void mkslot(int o, int by, int h, int w,
                                       const float* xb, const float*& p, float& sc) {
    const int dh2 = by >> 4, dw2 = by & 15;
    const bool valid = ((unsigned)(h + dh2 - 2) < (unsigned)HW) &
                       ((unsigned)(w + dw2 - 2) < (unsigned)HW);
    sc = valid ? 1.0f : 0.0f;
    p = xb + (valid ? o : 0);
}

// ---- fused kernel: one float4 item/thread, dense stores, forced-MLP conv ----
__global__ __launch_bounds__(256) void fused_kernel(const float* __restrict__ x,
                                                    const float4* __restrict__ wvtab,
                                                    const int4* __restrict__ offtab,
                                                    const int2* __restrict__ dhwtab,
                                                    const int* __restrict__ ntap,
                                                    const int* __restrict__ nbmax,
                                                    float* __restrict__ out) {
    // Bijective chunked XCD swizzle (m204): contiguous grid ranges per XCD.
    const int q = NWG / NXCD, r = NWG % NXCD;
    int xcd = blockIdx.x & (NXCD - 1);
    int idx = blockIdx.x >> 3;
    int swz = (xcd < r ? xcd * (q + 1) : r * (q + 1) + (xcd - r) * q) + idx;

    int t = swz * 256 + threadIdx.x;
    int g = t % GROUPS;
    int pixel = t / GROUPS;
    int rem = pixel % IMG;
    int h = rem / HW;
    int w = rem - h * HW;

    int base = pixel * CH + g * 4;
    const float* xb = x + base;
    float4 acc = *reinterpret_cast<const float4*>(xb);     // residual

    const int nt = ntap[g];
    if (nt > 0) {                                          // ONE exec-masked region
        const int nb = *nbmax;
        for (int b = 0; b < nb; ++b) {
            // one 16B + one 8B L1-hot load yields ALL 8 slot descriptors
            const int4 of = offtab[b * GROUPS + g];
            const int2 dd = dhwtab[b * GROUPS + g];
            // weights: 8 independent L1-hot loads (compiler clusters them)
            const float4* wrow = wvtab + (size_t)b * 8 * GROUPS + g;
            const float4 w0 = wrow[0 * GROUPS], w1 = wrow[1 * GROUPS];
            const float4 w2 = wrow[2 * GROUPS], w3 = wrow[3 * GROUPS];
            const float4 w4 = wrow[4 * GROUPS], w5 = wrow[5 * GROUPS];
            const float4 w6 = wrow[6 * GROUPS], w7 = wrow[7 * GROUPS];

            const float *p0, *p1, *p2, *p3, *p4, *p5, *p6, *p7;
            float s0, s1, s2, s3, s4, s5, s6, s7;
            mkslot((of.x << 16) >> 16, dd.x & 0xFF, h, w, xb, p0, s0);
            mkslot(of.x >> 16, (dd.x >> 8) & 0xFF, h, w, xb, p1, s1);
            mkslot((of.y << 16) >> 16, (dd.x >> 16) & 0xFF, h, w, xb, p2, s2);
            mkslot(of.y >> 16, (dd.x >> 24) & 0xFF, h, w, xb, p3, s3);
            mkslot((of.z << 16) >> 16, dd.y & 0xFF, h, w, xb, p4, s4);
            mkslot(of.z >> 16, (dd.y >> 8) & 0xFF, h, w, xb, p5, s5);
            mkslot((of.w << 16) >> 16, (dd.y >> 16) & 0xFF, h, w, xb, p6, s6);
            mkslot(of.w >> 16, (dd.y >> 24) & 0xFF, h, w, xb, p7, s7);

            // 8 tap loads forced in flight (compiler cannot re-roll inline asm)
            float4 v0, v1, v2, v3, v4, v5, v6, v7;
            asm volatile("global_load_dwordx4 %0, %1, off" : "=v"(v0) : "v"(p0));
            asm volatile("global_load_dwordx4 %0, %1, off" : "=v"(v1) : "v"(p1));
            asm volatile("global_load_dwordx4 %0, %1, off" : "=v"(v2) : "v"(p2));
            asm volatile("global_load_dwordx4 %0, %1, off" : "=v"(v3) : "v"(p3));
            asm volatile("global_load_dwordx4 %0, %1, off" : "=v"(v4) : "v"(p4));
            asm volatile("global_load_dwordx4 %0, %1, off" : "=v"(v5) : "v"(p5));
            asm volatile("global_load_dwordx4 %0, %1, off" : "=v"(v6) : "v"(p6));
            asm volatile("global_load_dwordx4 %0, %1, off" : "=v"(v7) : "v"(p7));
            // drain our asm loads (+ any compiler loads); fence against hoisting
            asm volatile("s_waitcnt vmcnt(0)" ::: "memory");
            __builtin_amdgcn_sched_barrier(0);

            acc.x += (w0.x * s0) * v0.x; acc.y += (w0.y * s0) * v0.y;
            acc.z += (w0.z * s0) * v0.z; acc.w += (w0.w * s0) * v0.w;
            acc.x += (w1.x * s1) * v1.x; acc.y += (w1.y * s1) * v1.y;
            acc.z += (w1.z * s1) * v1.z; acc.w += (w1.w * s1) * v1.w;
            acc.x += (w2.x * s2) * v2.x; acc.y += (w2.y * s2) * v2.y;
            acc.z += (w2.z * s2) * v2.z; acc.w += (w2.w * s2) * v2.w;
            acc.x += (w3.x * s3) * v3.x; acc.y += (w3.y * s3) * v3.y;
            acc.z += (w3.z * s3) * v3.z; acc.w += (w3.w * s3) * v3.w;
            acc.x += (w4.x * s4) * v4.x; acc.y += (w4.y * s4) * v4.y;
            acc.z += (w4.z * s4) * v4.z; acc.w += (w4.w * s4) * v4.w;
            acc.x += (w5.x * s5) * v5.x; acc.y += (w5.y * s5) * v5.y;
            acc.z += (w5.z * s5) * v5.z; acc.w += (w5.w * s5) * v5.w;
            acc.x += (w6.x * s6) * v6.x; acc.y += (w6.y * s6) * v6.y;
            acc.z += (w6.z * s6) * v6.z; acc.w += (w6.w * s6) * v6.w;
            acc.x += (w7.x * s7) * v7.x; acc.y += (w7.y * s7) * v7.y;
            acc.z += (w7.z * s7) * v7.z; acc.w += (w7.w * s7) * v7.w;
        }
    }
    // single dense store point per wave: full 1KB lines, no partial-line RMW
    __builtin_nontemporal_store(acc.x, out + base + 0);
    __builtin_nontemporal_store(acc.y, out + base + 1);
    __builtin_nontemporal_store(acc.z, out + base + 2);
    __builtin_nontemporal_store(acc.w, out + base + 3);
}

// ---- Fallback (ws too small): monolithic, reads raw k — correctness only ----
__global__ __launch_bounds__(256) void fallback_kernel(const float* __restrict__ x,
                                                       const float* __restrict__ kraw,
                                                       float* __restrict__ out) {
    int t = blockIdx.x * 256 + threadIdx.x;
    if (t >= TOTALF4) return;
    int g = t % GROUPS;
    int pixel = t / GROUPS;
    int rem = pixel % IMG;
    int h = rem / HW;
    int w = rem - h * HW;
    int base = pixel * CH + g * 4;
    const float4 xc = *reinterpret_cast<const float4*>(x + base);
    float4 acc = make_float4(xc.x, xc.y, xc.z, xc.w);
#pragma unroll
    for (int dh = -2; dh <= 2; ++dh)
#pragma unroll
        for (int dw = -2; dw <= 2; ++dw) {
            const int tap = (dh + 2) * 5 + (dw + 2);
            const bool valid = ((unsigned)(h + dh) < (unsigned)HW) &
                               ((unsigned)(w + dw) < (unsigned)HW);
            const float vs = valid ? 1.0f : 0.0f;
            const int off = valid ? (dh * HSTRIDE + dw * WSTRIDE) : 0;
            const float4 xv = *reinterpret_cast<const float4*>(x + base + off);
            acc.x += (kraw[(g * 4 + 0) * TAPS + tap] * vs) * xv.x;
            acc.y += (kraw[(g * 4 + 1) * TAPS + tap] * vs) * xv.y;
            acc.z += (kraw[(g * 4 + 2) * TAPS + tap] * vs) * xv.z;
            acc.w += (kraw[(g * 4 + 3) * TAPS + tap] * vs) * xv.w;
        }
    *reinterpret_cast<float4*>(out + base) = acc;
}

extern "C" void kernel_launch(void* const* d_in, const int* in_sizes, int n_in,
                              void* d_out, int out_size, void* d_ws, size_t ws_size,
                              hipStream_t stream) {
    const float* x = (const float*)d_in[0];
    const float* k = (const float*)d_in[1];
    float* out = (float*)d_out;

    const size_t sz_wvtab = (size_t)NSLOTCAP * GROUPS * sizeof(float4);  // 12288
    const size_t sz_offtab = (size_t)NBATCH * GROUPS * sizeof(int4);     // 1536
    const size_t sz_dhwtab = (size_t)NBATCH * GROUPS * sizeof(int2);     // 768
    const size_t sz_ntap = GROUPS * sizeof(int);
    const size_t ws_need = sz_wvtab + sz_offtab + sz_dhwtab + sz_ntap + sizeof(int);

    if (ws_size >= ws_need) {
        char* p = (char*)d_ws;
        float4* wvtab = (float4*)p;  p += sz_wvtab;
        int4* offtab = (int4*)p;     p += sz_offtab;
        int2* dhwtab = (int2*)p;     p += sz_dhwtab;
        int* ntap = (int*)p;         p += sz_ntap;
        int* nbmax = (int*)p;

        repack_kernel<<<1, 64, 0, stream>>>(k, wvtab, offtab, dhwtab, ntap, nbmax);
        fused_kernel<<<NWG, 256, 0, stream>>>(x, wvtab, offtab, dhwtab, ntap,
                                              nbmax, out);
    } else {
        fallback_kernel<<<NWG, 256, 0, stream>>>(x, k, out);
    }
}